// Round 2
// baseline (1917.593 us; speedup 1.0000x reference)
//
#include <hip/hip_runtime.h>
#include <hip/hip_bf16.h>
#include <math.h>

// PropagationBlock: GNN edge-message propagation, NV=32, DIM=3.
// Round 2: replace 192M memory-side f32 atomics (750 MB RMW write-through,
// the round-1 bottleneck) with on-device CSR build + bf16 message buffer +
// node-parallel gather (f32 register accumulation, fused mix+activation).
// Falls back to the atomic path if ws_size is too small.

#define NVEC 32

__device__ __forceinline__ float silu_f(float x) { return x / (1.0f + __expf(-x)); }

// ---------------------------------------------------------------- prep mats
// P = C1+C2, Q = C2-C1 with C1=(n2e_M1@Mvv)/2, C2=(n2e_M2@Mvv)/4, Mvv=(vv1+vv2)/2
// R = (e2n_M1+e2n_M2)/2, S = (e2n_M2-e2n_M1)/2
__global__ __launch_bounds__(1024) void prep_mats_kernel(
    const float* __restrict__ n2e_M1, const float* __restrict__ n2e_M2,
    const float* __restrict__ vv_M1, const float* __restrict__ vv_M2,
    const float* __restrict__ e2n_M1, const float* __restrict__ e2n_M2,
    float* __restrict__ PQRS) {
  __shared__ float Mvv[32][32];
  int j = threadIdx.x & 31, i = threadIdx.x >> 5;
  Mvv[i][j] = 0.5f * (vv_M1[i * 32 + j] + vv_M2[i * 32 + j]);
  __syncthreads();
  float c1 = 0.f, c2 = 0.f;
#pragma unroll
  for (int k = 0; k < 32; k++) {
    c1 += n2e_M1[i * 32 + k] * Mvv[k][j];
    c2 += n2e_M2[i * 32 + k] * Mvv[k][j];
  }
  c1 *= 0.5f;
  c2 *= 0.25f;
  PQRS[0 * 1024 + i * 32 + j] = c1 + c2;                                  // P
  PQRS[1 * 1024 + i * 32 + j] = c2 - c1;                                  // Q
  PQRS[2 * 1024 + i * 32 + j] = 0.5f * (e2n_M1[i * 32 + j] + e2n_M2[i * 32 + j]); // R
  PQRS[3 * 1024 + i * 32 + j] = 0.5f * (e2n_M2[i * 32 + j] - e2n_M1[i * 32 + j]); // S
}

// ---------------------------------------------------------------- premix
// xn2 = cos(a)*xn + sin(a)*(((xn@M) * attr) @ M^T)   ; 32 lanes per node
__global__ __launch_bounds__(256) void node_premix_kernel(
    const float* __restrict__ xn, const float* __restrict__ xn_attr,
    const float* __restrict__ ms_M, const float* __restrict__ ms_w,
    float* __restrict__ xn2, int n_nodes) {
  __shared__ float M[32][33];
  for (int idx = threadIdx.x; idx < 1024; idx += blockDim.x)
    M[idx >> 5][idx & 31] = ms_M[idx];
  __syncthreads();

  int lane = threadIdx.x & 31;
  int grp = blockIdx.x * (blockDim.x >> 5) + (threadIdx.x >> 5);
  if (grp >= n_nodes) return;

  float angle = 0.1f * ms_w[0];
  float ca = cosf(angle), sa = sinf(angle);

  const float* xp = xn + (size_t)grp * 96;
  float x0 = xp[lane], x1 = xp[32 + lane], x2 = xp[64 + lane];

  float t0 = 0.f, t1 = 0.f, t2 = 0.f;
#pragma unroll
  for (int v = 0; v < 32; v++) {
    float m = M[v][lane];
    t0 += __shfl(x0, v, 32) * m;
    t1 += __shfl(x1, v, 32) * m;
    t2 += __shfl(x2, v, 32) * m;
  }
  float attr = xn_attr[(size_t)grp * 32 + lane];
  t0 *= attr; t1 *= attr; t2 *= attr;

  float y0 = 0.f, y1 = 0.f, y2 = 0.f;
#pragma unroll
  for (int s = 0; s < 32; s++) {
    float m = M[lane][s];
    y0 += __shfl(t0, s, 32) * m;
    y1 += __shfl(t1, s, 32) * m;
    y2 += __shfl(t2, s, 32) * m;
  }

  float* op = xn2 + (size_t)grp * 96;
  op[lane]      = ca * x0 + sa * y0;
  op[32 + lane] = ca * x1 + sa * y1;
  op[64 + lane] = ca * x2 + sa * y2;
}

// ---------------------------------------------------------------- CSR build
__global__ __launch_bounds__(256) void degree_kernel(
    const int* __restrict__ xe_src, const int* __restrict__ xe_dst,
    unsigned* __restrict__ cnt, int n_edges, int n_nodes) {
  int e = blockIdx.x * blockDim.x + threadIdx.x;
  if (e >= n_edges) return;
  atomicAdd(&cnt[xe_dst[e]], 1u);
  atomicAdd(&cnt[n_nodes + xe_src[e]], 1u);
}

// single-block exclusive scan over n counters -> offs[0..n] ; cursors = copy
__global__ __launch_bounds__(1024) void scan_kernel(
    const unsigned* __restrict__ cnt, unsigned* __restrict__ offs,
    unsigned* __restrict__ cursors, int n, int strip) {
  int tid = threadIdx.x;
  int lane = tid & 63, wid = tid >> 6;
  size_t s0 = (size_t)tid * strip;

  unsigned tot = 0;
  for (int i = 0; i < strip; i++) {
    size_t idx = s0 + i;
    if (idx < (size_t)n) tot += cnt[idx];
  }
  unsigned v = tot;
  for (int off = 1; off < 64; off <<= 1) {
    unsigned t = __shfl_up(v, off, 64);
    if (lane >= off) v += t;
  }
  __shared__ unsigned wsum[16];
  __shared__ unsigned wpre[17];
  if (lane == 63) wsum[wid] = v;
  __syncthreads();
  if (tid == 0) {
    unsigned c = 0;
    for (int w = 0; w < 16; w++) { wpre[w] = c; c += wsum[w]; }
    wpre[16] = c;
  }
  __syncthreads();
  unsigned run = wpre[wid] + (v - tot);  // exclusive prefix of this strip
  for (int i = 0; i < strip; i++) {
    size_t idx = s0 + i;
    if (idx < (size_t)n) {
      offs[idx] = run;
      cursors[idx] = run;
      run += cnt[idx];
    }
  }
  if (tid == 0) offs[n] = wpre[16];
}

__global__ __launch_bounds__(256) void fill_kernel(
    const int* __restrict__ xe_src, const int* __restrict__ xe_dst,
    unsigned* __restrict__ cursors, unsigned* __restrict__ list,
    int n_edges, int n_nodes) {
  int e = blockIdx.x * blockDim.x + threadIdx.x;
  if (e >= n_edges) return;
  unsigned s1 = atomicAdd(&cursors[xe_dst[e]], 1u);
  list[s1] = (unsigned)e;
  unsigned s2 = atomicAdd(&cursors[n_nodes + xe_src[e]], 1u);
  list[s2] = (unsigned)e;
}

// ---------------------------------------------------------------- edge msgs
// m_e = w2 * ((w1*xs)@P + (w1*xd)@Q), written once as bf16 (no atomics)
__global__ __launch_bounds__(256) void edge_msg_kernel(
    const float* __restrict__ xn2, const float* __restrict__ xe_attr,
    const int* __restrict__ xe_src, const int* __restrict__ xe_dst,
    const float* __restrict__ fc1_w, const float* __restrict__ fc1_b,
    const float* __restrict__ fc2_w, const float* __restrict__ fc2_b,
    const float* __restrict__ Pg, const float* __restrict__ Qg,
    __hip_bfloat16* __restrict__ msg, int n_edges) {
  __shared__ float P[32][32], Q[32][32];
  for (int idx = threadIdx.x; idx < 1024; idx += blockDim.x) {
    P[idx >> 5][idx & 31] = Pg[idx];
    Q[idx >> 5][idx & 31] = Qg[idx];
  }
  __syncthreads();

  int lane = threadIdx.x & 31;
  int egrp = blockIdx.x * (blockDim.x >> 5) + (threadIdx.x >> 5);
  int estride = gridDim.x * (blockDim.x >> 5);

  float f1w = fc1_w[lane], f1b = fc1_b[lane];
  float f2w = fc2_w[lane], f2b = fc2_b[lane];

  for (int e = egrp; e < n_edges; e += estride) {
    float ea = xe_attr[e];
    float w1 = silu_f(ea * f1w + f1b);
    float w2 = silu_f(ea * f2w + f2b);
    int sn = xe_src[e], dn = xe_dst[e];
    const float* xs = xn2 + (size_t)sn * 96;
    const float* xd = xn2 + (size_t)dn * 96;
    float a0 = w1 * xs[lane], a1 = w1 * xs[32 + lane], a2 = w1 * xs[64 + lane];
    float b0 = w1 * xd[lane], b1 = w1 * xd[32 + lane], b2 = w1 * xd[64 + lane];

    float g0 = 0.f, g1 = 0.f, g2 = 0.f;
#pragma unroll
    for (int v = 0; v < 32; v++) {
      float p = P[v][lane], q = Q[v][lane];
      g0 += __shfl(a0, v, 32) * p + __shfl(b0, v, 32) * q;
      g1 += __shfl(a1, v, 32) * p + __shfl(b1, v, 32) * q;
      g2 += __shfl(a2, v, 32) * p + __shfl(b2, v, 32) * q;
    }
    __hip_bfloat16* m = msg + (size_t)e * 96;
    m[lane]      = __float2bfloat16(g0 * w2);
    m[32 + lane] = __float2bfloat16(g1 * w2);
    m[64 + lane] = __float2bfloat16(g2 * w2);
  }
}

// ---------------------------------------------------------------- gather
// acc1 = sum msg over in-list, acc2 over out-list; out = acc1@R + acc2@S;
// activation x*tanh(||x||) fused. f32 accumulation in registers.
__global__ __launch_bounds__(256) void gather_kernel(
    const __hip_bfloat16* __restrict__ msg, const unsigned* __restrict__ offs,
    const unsigned* __restrict__ list,
    const float* __restrict__ Rg, const float* __restrict__ Sg,
    float* __restrict__ out, int n_nodes) {
  __shared__ float R[32][32], S[32][32];
  for (int idx = threadIdx.x; idx < 1024; idx += blockDim.x) {
    R[idx >> 5][idx & 31] = Rg[idx];
    S[idx >> 5][idx & 31] = Sg[idx];
  }
  __syncthreads();

  int lane = threadIdx.x & 31;
  int grp = blockIdx.x * (blockDim.x >> 5) + (threadIdx.x >> 5);
  if (grp >= n_nodes) return;

  float a0 = 0.f, a1 = 0.f, a2 = 0.f, b0 = 0.f, b1 = 0.f, b2 = 0.f;

  unsigned st = offs[grp], en = offs[grp + 1];
  for (unsigned i = st; i < en; i++) {
    const __hip_bfloat16* m = msg + (size_t)list[i] * 96;
    a0 += __bfloat162float(m[lane]);
    a1 += __bfloat162float(m[32 + lane]);
    a2 += __bfloat162float(m[64 + lane]);
  }
  unsigned st2 = offs[n_nodes + grp], en2 = offs[n_nodes + grp + 1];
  for (unsigned i = st2; i < en2; i++) {
    const __hip_bfloat16* m = msg + (size_t)list[i] * 96;
    b0 += __bfloat162float(m[lane]);
    b1 += __bfloat162float(m[32 + lane]);
    b2 += __bfloat162float(m[64 + lane]);
  }

  float y0 = 0.f, y1 = 0.f, y2 = 0.f;
#pragma unroll
  for (int v = 0; v < 32; v++) {
    float r = R[v][lane], s = S[v][lane];
    y0 += __shfl(a0, v, 32) * r + __shfl(b0, v, 32) * s;
    y1 += __shfl(a1, v, 32) * r + __shfl(b1, v, 32) * s;
    y2 += __shfl(a2, v, 32) * r + __shfl(b2, v, 32) * s;
  }

  float nrm = sqrtf(y0 * y0 + y1 * y1 + y2 * y2);
  float t = tanhf(nrm);

  float* op = out + (size_t)grp * 96;
  op[lane]      = y0 * t;
  op[32 + lane] = y1 * t;
  op[64 + lane] = y2 * t;
}

// ---------------------------------------------------------------- fallback (round-1 atomic path)
__global__ __launch_bounds__(256) void edge_kernel_atomic(
    const float* __restrict__ xn2, const float* __restrict__ xe_attr,
    const int* __restrict__ xe_src, const int* __restrict__ xe_dst,
    const float* __restrict__ fc1_w, const float* __restrict__ fc1_b,
    const float* __restrict__ fc2_w, const float* __restrict__ fc2_b,
    const float* __restrict__ Pg, const float* __restrict__ Qg,
    float* __restrict__ acc1, float* __restrict__ acc2, int n_edges) {
  __shared__ float P[32][32], Q[32][32];
  for (int idx = threadIdx.x; idx < 1024; idx += blockDim.x) {
    P[idx >> 5][idx & 31] = Pg[idx];
    Q[idx >> 5][idx & 31] = Qg[idx];
  }
  __syncthreads();
  int lane = threadIdx.x & 31;
  int egrp = blockIdx.x * (blockDim.x >> 5) + (threadIdx.x >> 5);
  int estride = gridDim.x * (blockDim.x >> 5);
  float f1w = fc1_w[lane], f1b = fc1_b[lane];
  float f2w = fc2_w[lane], f2b = fc2_b[lane];
  for (int e = egrp; e < n_edges; e += estride) {
    float ea = xe_attr[e];
    float w1 = silu_f(ea * f1w + f1b);
    float w2 = silu_f(ea * f2w + f2b);
    int sn = xe_src[e], dn = xe_dst[e];
    const float* xs = xn2 + (size_t)sn * 96;
    const float* xd = xn2 + (size_t)dn * 96;
    float a0 = w1 * xs[lane], a1 = w1 * xs[32 + lane], a2 = w1 * xs[64 + lane];
    float b0 = w1 * xd[lane], b1 = w1 * xd[32 + lane], b2 = w1 * xd[64 + lane];
    float g0 = 0.f, g1 = 0.f, g2 = 0.f;
#pragma unroll
    for (int v = 0; v < 32; v++) {
      float p = P[v][lane], q = Q[v][lane];
      g0 += __shfl(a0, v, 32) * p + __shfl(b0, v, 32) * q;
      g1 += __shfl(a1, v, 32) * p + __shfl(b1, v, 32) * q;
      g2 += __shfl(a2, v, 32) * p + __shfl(b2, v, 32) * q;
    }
    g0 *= w2; g1 *= w2; g2 *= w2;
    float* p1 = acc1 + (size_t)dn * 96;
    float* p2 = acc2 + (size_t)sn * 96;
    atomicAdd(&p1[lane], g0);
    atomicAdd(&p1[32 + lane], g1);
    atomicAdd(&p1[64 + lane], g2);
    atomicAdd(&p2[lane], g0);
    atomicAdd(&p2[32 + lane], g1);
    atomicAdd(&p2[64 + lane], g2);
  }
}

__global__ __launch_bounds__(256) void node_post_kernel(
    const float* __restrict__ acc1, const float* __restrict__ acc2,
    const float* __restrict__ Rg, const float* __restrict__ Sg,
    float* __restrict__ out, int n_nodes) {
  __shared__ float R[32][32], S[32][32];
  for (int idx = threadIdx.x; idx < 1024; idx += blockDim.x) {
    R[idx >> 5][idx & 31] = Rg[idx];
    S[idx >> 5][idx & 31] = Sg[idx];
  }
  __syncthreads();
  int lane = threadIdx.x & 31;
  int grp = blockIdx.x * (blockDim.x >> 5) + (threadIdx.x >> 5);
  if (grp >= n_nodes) return;
  const float* a = acc1 + (size_t)grp * 96;
  const float* b = acc2 + (size_t)grp * 96;
  float a0 = a[lane], a1 = a[32 + lane], a2 = a[64 + lane];
  float b0 = b[lane], b1 = b[32 + lane], b2 = b[64 + lane];
  float y0 = 0.f, y1 = 0.f, y2 = 0.f;
#pragma unroll
  for (int v = 0; v < 32; v++) {
    float r = R[v][lane], s = S[v][lane];
    y0 += __shfl(a0, v, 32) * r + __shfl(b0, v, 32) * s;
    y1 += __shfl(a1, v, 32) * r + __shfl(b1, v, 32) * s;
    y2 += __shfl(a2, v, 32) * r + __shfl(b2, v, 32) * s;
  }
  float nrm = sqrtf(y0 * y0 + y1 * y1 + y2 * y2);
  float t = tanhf(nrm);
  float* op = out + (size_t)grp * 96;
  op[lane]      = y0 * t;
  op[32 + lane] = y1 * t;
  op[64 + lane] = y2 * t;
}

// ---------------------------------------------------------------- launch
extern "C" void kernel_launch(void* const* d_in, const int* in_sizes, int n_in,
                              void* d_out, int out_size, void* d_ws, size_t ws_size,
                              hipStream_t stream) {
  const float* xn      = (const float*)d_in[0];
  const float* xn_attr = (const float*)d_in[1];
  const float* xe_attr = (const float*)d_in[2];
  const int*   xe_src  = (const int*)d_in[3];
  const int*   xe_dst  = (const int*)d_in[4];
  const float* ms_M    = (const float*)d_in[5];
  const float* ms_w    = (const float*)d_in[6];
  const float* fc1_w   = (const float*)d_in[7];
  const float* fc1_b   = (const float*)d_in[8];
  const float* fc2_w   = (const float*)d_in[9];
  const float* fc2_b   = (const float*)d_in[10];
  const float* n2e_M1  = (const float*)d_in[11];
  const float* n2e_M2  = (const float*)d_in[12];
  const float* vv_M1   = (const float*)d_in[13];
  const float* vv_M2   = (const float*)d_in[14];
  const float* e2n_M1  = (const float*)d_in[15];
  const float* e2n_M2  = (const float*)d_in[16];

  int n_nodes = in_sizes[0] / 96;
  int n_edges = in_sizes[2];

  // ---- ws layout (CSR path)
  char* base = (char*)d_ws;
  size_t off = 0;
  float* PQRS = (float*)(base + off); off += 4096 * sizeof(float);
  __hip_bfloat16* msg = (__hip_bfloat16*)(base + off);
  off += (size_t)n_edges * 96 * sizeof(__hip_bfloat16);
  unsigned* cnt = (unsigned*)(base + off); off += (size_t)2 * n_nodes * 4;
  unsigned* offs = (unsigned*)(base + off); off += ((size_t)2 * n_nodes + 1) * 4;
  off = (off + 255) & ~(size_t)255;
  unsigned* cursors = (unsigned*)(base + off); off += (size_t)2 * n_nodes * 4;
  unsigned* list = (unsigned*)(base + off); off += (size_t)2 * n_edges * 4;
  size_t need = off;

  float* xn2 = (float*)d_out;  // d_out doubles as premix scratch

  prep_mats_kernel<<<1, 1024, 0, stream>>>(n2e_M1, n2e_M2, vv_M1, vv_M2, e2n_M1, e2n_M2, PQRS);

  int nblk = (n_nodes + 7) / 8;
  node_premix_kernel<<<nblk, 256, 0, stream>>>(xn, xn_attr, ms_M, ms_w, xn2, n_nodes);

  int eblk = (n_edges + 255) / 256;

  if (ws_size >= need) {
    // -------- CSR path
    hipMemsetAsync(cnt, 0, (size_t)2 * n_nodes * 4, stream);
    degree_kernel<<<eblk, 256, 0, stream>>>(xe_src, xe_dst, cnt, n_edges, n_nodes);
    int n2 = 2 * n_nodes;
    int strip = (n2 + 1023) / 1024;
    scan_kernel<<<1, 1024, 0, stream>>>(cnt, offs, cursors, n2, strip);
    fill_kernel<<<eblk, 256, 0, stream>>>(xe_src, xe_dst, cursors, list, n_edges, n_nodes);

    edge_msg_kernel<<<4096, 256, 0, stream>>>(xn2, xe_attr, xe_src, xe_dst,
                                              fc1_w, fc1_b, fc2_w, fc2_b,
                                              PQRS, PQRS + 1024, msg, n_edges);

    gather_kernel<<<nblk, 256, 0, stream>>>(msg, offs, list, PQRS + 2048, PQRS + 3072,
                                            (float*)d_out, n_nodes);
  } else {
    // -------- fallback: round-1 atomic path (needs ~38.4 MB)
    float* acc1 = (float*)d_ws + 4096;
    float* acc2 = acc1 + (size_t)n_nodes * 96;
    hipMemsetAsync(acc1, 0, (size_t)n_nodes * 96 * 2 * sizeof(float), stream);
    edge_kernel_atomic<<<4096, 256, 0, stream>>>(xn2, xe_attr, xe_src, xe_dst,
                                                 fc1_w, fc1_b, fc2_w, fc2_b,
                                                 PQRS, PQRS + 1024, acc1, acc2, n_edges);
    node_post_kernel<<<nblk, 256, 0, stream>>>(acc1, acc2, PQRS + 2048, PQRS + 3072,
                                               (float*)d_out, n_nodes);
  }
}

// Round 3
// 827.234 us; speedup vs baseline: 2.3181x; 2.3181x over previous
//
#include <hip/hip_runtime.h>
#include <math.h>

// PropagationBlock round 3: MFMA edge kernel + f32 atomic scatter.
// Round-2 finding: edge kernel was shuffle-pipe-bound (~96 wave ds-ops/edge),
// NOT atomic-bound (atomics ran hidden). MFMA replaces the shuffle matvec.

typedef __attribute__((ext_vector_type(8))) short bf16x8;  // 8 bf16 (4 VGPRs)
typedef __attribute__((ext_vector_type(4))) float f32x4;

__device__ __forceinline__ float silu_f(float x) { return x / (1.0f + __expf(-x)); }

__device__ __forceinline__ unsigned cvt_pk_bf16(float lo, float hi) {
  unsigned r;
  asm("v_cvt_pk_bf16_f32 %0, %1, %2" : "=v"(r) : "v"(lo), "v"(hi));
  return r;
}
__device__ __forceinline__ float bf_lo(unsigned w) { return __uint_as_float(w << 16); }
__device__ __forceinline__ float bf_hi(unsigned w) { return __uint_as_float(w & 0xFFFF0000u); }

// ---------------------------------------------------------------- prep mats
// P = C1+C2, Q = C2-C1 ; C1=(n2e_M1@Mvv)/2, C2=(n2e_M2@Mvv)/4, Mvv=(vv1+vv2)/2
// R = (e2n_M1+e2n_M2)/2, S = (e2n_M2-e2n_M1)/2
__global__ __launch_bounds__(1024) void prep_mats_kernel(
    const float* __restrict__ n2e_M1, const float* __restrict__ n2e_M2,
    const float* __restrict__ vv_M1, const float* __restrict__ vv_M2,
    const float* __restrict__ e2n_M1, const float* __restrict__ e2n_M2,
    float* __restrict__ PQRS) {
  __shared__ float Mvv[32][32];
  int j = threadIdx.x & 31, i = threadIdx.x >> 5;
  Mvv[i][j] = 0.5f * (vv_M1[i * 32 + j] + vv_M2[i * 32 + j]);
  __syncthreads();
  float c1 = 0.f, c2 = 0.f;
#pragma unroll
  for (int k = 0; k < 32; k++) {
    c1 += n2e_M1[i * 32 + k] * Mvv[k][j];
    c2 += n2e_M2[i * 32 + k] * Mvv[k][j];
  }
  c1 *= 0.5f;
  c2 *= 0.25f;
  PQRS[0 * 1024 + i * 32 + j] = c1 + c2;                                          // P [k][col]
  PQRS[1 * 1024 + i * 32 + j] = c2 - c1;                                          // Q [k][col]
  PQRS[2 * 1024 + i * 32 + j] = 0.5f * (e2n_M1[i * 32 + j] + e2n_M2[i * 32 + j]); // R
  PQRS[3 * 1024 + i * 32 + j] = 0.5f * (e2n_M2[i * 32 + j] - e2n_M1[i * 32 + j]); // S
}

// ---------------------------------------------------------------- premix
// xn2b = bf16( cos(a)*xn + sin(a)*(((xn@M)*attr)@M^T) )
__global__ __launch_bounds__(256) void node_premix_kernel(
    const float* __restrict__ xn, const float* __restrict__ xn_attr,
    const float* __restrict__ ms_M, const float* __restrict__ ms_w,
    unsigned short* __restrict__ xn2b, int n_nodes) {
  __shared__ float M[32][33];
  for (int idx = threadIdx.x; idx < 1024; idx += blockDim.x)
    M[idx >> 5][idx & 31] = ms_M[idx];
  __syncthreads();

  int lane = threadIdx.x & 31;
  int grp = blockIdx.x * (blockDim.x >> 5) + (threadIdx.x >> 5);
  if (grp >= n_nodes) return;

  float angle = 0.1f * ms_w[0];
  float ca = cosf(angle), sa = sinf(angle);

  const float* xp = xn + (size_t)grp * 96;
  float x0 = xp[lane], x1 = xp[32 + lane], x2 = xp[64 + lane];

  float t0 = 0.f, t1 = 0.f, t2 = 0.f;
#pragma unroll
  for (int v = 0; v < 32; v++) {
    float m = M[v][lane];
    t0 += __shfl(x0, v, 32) * m;
    t1 += __shfl(x1, v, 32) * m;
    t2 += __shfl(x2, v, 32) * m;
  }
  float attr = xn_attr[(size_t)grp * 32 + lane];
  t0 *= attr; t1 *= attr; t2 *= attr;

  float y0 = 0.f, y1 = 0.f, y2 = 0.f;
#pragma unroll
  for (int s = 0; s < 32; s++) {
    float m = M[lane][s];
    y0 += __shfl(t0, s, 32) * m;
    y1 += __shfl(t1, s, 32) * m;
    y2 += __shfl(t2, s, 32) * m;
  }

  unsigned short* op = xn2b + (size_t)grp * 96;
  op[lane]      = (unsigned short)cvt_pk_bf16(ca * x0 + sa * y0, 0.f);
  op[32 + lane] = (unsigned short)cvt_pk_bf16(ca * x1 + sa * y1, 0.f);
  op[64 + lane] = (unsigned short)cvt_pk_bf16(ca * x2 + sa * y2, 0.f);
}

// ---------------------------------------------------------------- edge MFMA
// Per wave-tile of 16 edges: C[16e x 32v] = (W1.*xs)@P + (W1.*xd)@Q via
// 12x mfma_f32_16x16x32_bf16; epilogue applies W2 and atomically scatters
// into acc1[dst], acc2[src].
__global__ __launch_bounds__(256) void edge_mfma_kernel(
    const unsigned short* __restrict__ xn2b, const float* __restrict__ xe_attr,
    const int* __restrict__ xe_src, const int* __restrict__ xe_dst,
    const float* __restrict__ fc1_w, const float* __restrict__ fc1_b,
    const float* __restrict__ fc2_w, const float* __restrict__ fc2_b,
    const float* __restrict__ Pg, const float* __restrict__ Qg,
    float* __restrict__ acc1, float* __restrict__ acc2, int n_edges) {
  int lane = threadIdx.x & 63;
  int row16 = lane & 15;   // edge-row within tile / output col for B,C
  int koct = lane >> 4;    // k-octet 0..3

  // B fragments (P,Q split into two 16-col tiles), bf16 RNE, kept in regs.
  // B-frag element j of lane = B[k = koct*8+j][col = lane&15].
  union { unsigned u[4]; bf16x8 v; } PB0, PB1, QB0, QB1;
#pragma unroll
  for (int w = 0; w < 4; w++) {
    int k0 = koct * 8 + 2 * w;
    PB0.u[w] = cvt_pk_bf16(Pg[k0 * 32 + row16],      Pg[(k0 + 1) * 32 + row16]);
    PB1.u[w] = cvt_pk_bf16(Pg[k0 * 32 + row16 + 16], Pg[(k0 + 1) * 32 + row16 + 16]);
    QB0.u[w] = cvt_pk_bf16(Qg[k0 * 32 + row16],      Qg[(k0 + 1) * 32 + row16]);
    QB1.u[w] = cvt_pk_bf16(Qg[k0 * 32 + row16 + 16], Qg[(k0 + 1) * 32 + row16 + 16]);
  }

  float f1wj[8], f1bj[8];
#pragma unroll
  for (int j = 0; j < 8; j++) {
    f1wj[j] = fc1_w[koct * 8 + j];
    f1bj[j] = fc1_b[koct * 8 + j];
  }
  float f2w0 = fc2_w[row16], f2b0 = fc2_b[row16];
  float f2w1 = fc2_w[row16 + 16], f2b1 = fc2_b[row16 + 16];

  int wid = blockIdx.x * (blockDim.x >> 6) + (threadIdx.x >> 6);
  int wstride = gridDim.x * (blockDim.x >> 6);
  int ntiles = (n_edges + 15) >> 4;

  for (int t = wid; t < ntiles; t += wstride) {
    int ebase = t << 4;
    int e = ebase + row16;
    int ec = e < n_edges ? e : n_edges - 1;
    int sn = xe_src[ec], dn = xe_dst[ec];
    float ea = xe_attr[ec];

    // W1[e][k] for this lane's 8 k values
    float w1[8];
#pragma unroll
    for (int j = 0; j < 8; j++) w1[j] = silu_f(ea * f1wj[j] + f1bj[j]);

    f32x4 c[3][2];
#pragma unroll
    for (int d = 0; d < 3; d++) {
      c[d][0] = f32x4{0.f, 0.f, 0.f, 0.f};
      c[d][1] = f32x4{0.f, 0.f, 0.f, 0.f};
    }

#pragma unroll
    for (int d = 0; d < 3; d++) {
      uint4 aw = *(const uint4*)(xn2b + (size_t)sn * 96 + d * 32 + koct * 8);
      uint4 bw = *(const uint4*)(xn2b + (size_t)dn * 96 + d * 32 + koct * 8);
      unsigned awa[4] = {aw.x, aw.y, aw.z, aw.w};
      unsigned bwa[4] = {bw.x, bw.y, bw.z, bw.w};
      union { unsigned u[4]; bf16x8 v; } AF, BF;
#pragma unroll
      for (int w = 0; w < 4; w++) {
        AF.u[w] = cvt_pk_bf16(bf_lo(awa[w]) * w1[2 * w], bf_hi(awa[w]) * w1[2 * w + 1]);
        BF.u[w] = cvt_pk_bf16(bf_lo(bwa[w]) * w1[2 * w], bf_hi(bwa[w]) * w1[2 * w + 1]);
      }
      c[d][0] = __builtin_amdgcn_mfma_f32_16x16x32_bf16(AF.v, PB0.v, c[d][0], 0, 0, 0);
      c[d][0] = __builtin_amdgcn_mfma_f32_16x16x32_bf16(BF.v, QB0.v, c[d][0], 0, 0, 0);
      c[d][1] = __builtin_amdgcn_mfma_f32_16x16x32_bf16(AF.v, PB1.v, c[d][1], 0, 0, 0);
      c[d][1] = __builtin_amdgcn_mfma_f32_16x16x32_bf16(BF.v, QB1.v, c[d][1], 0, 0, 0);
    }

    // Epilogue: lane owns C rows r' = koct*4+rr (edges ebase+r'), col = row16 (+16).
    float w2a[4], w2b[4];
    int sn2[4], dn2[4], ev2[4];
#pragma unroll
    for (int rr = 0; rr < 4; rr++) {
      int rp = koct * 4 + rr;
      float ea2 = __shfl(ea, rp, 16);
      sn2[rr] = __shfl(sn, rp, 16);
      dn2[rr] = __shfl(dn, rp, 16);
      ev2[rr] = (ebase + rp) < n_edges;
      w2a[rr] = silu_f(ea2 * f2w0 + f2b0);
      w2b[rr] = silu_f(ea2 * f2w1 + f2b1);
    }

#pragma unroll
    for (int d = 0; d < 3; d++) {
#pragma unroll
      for (int rr = 0; rr < 4; rr++) {
        if (!ev2[rr]) continue;
        float v0 = c[d][0][rr] * w2a[rr];
        float v1 = c[d][1][rr] * w2b[rr];
        float* a1 = acc1 + (size_t)dn2[rr] * 96 + d * 32 + row16;
        float* a2 = acc2 + (size_t)sn2[rr] * 96 + d * 32 + row16;
        atomicAdd(a1, v0);
        atomicAdd(a2, v0);
        atomicAdd(a1 + 16, v1);
        atomicAdd(a2 + 16, v1);
      }
    }
  }
}

// ---------------------------------------------------------------- node post
// out = acc1@R + acc2@S, then x * tanh(||x||_dim)
__global__ __launch_bounds__(256) void node_post_kernel(
    const float* __restrict__ acc1, const float* __restrict__ acc2,
    const float* __restrict__ Rg, const float* __restrict__ Sg,
    float* __restrict__ out, int n_nodes) {
  __shared__ float R[32][32], S[32][32];
  for (int idx = threadIdx.x; idx < 1024; idx += blockDim.x) {
    R[idx >> 5][idx & 31] = Rg[idx];
    S[idx >> 5][idx & 31] = Sg[idx];
  }
  __syncthreads();
  int lane = threadIdx.x & 31;
  int grp = blockIdx.x * (blockDim.x >> 5) + (threadIdx.x >> 5);
  if (grp >= n_nodes) return;
  const float* a = acc1 + (size_t)grp * 96;
  const float* b = acc2 + (size_t)grp * 96;
  float a0 = a[lane], a1 = a[32 + lane], a2 = a[64 + lane];
  float b0 = b[lane], b1 = b[32 + lane], b2 = b[64 + lane];
  float y0 = 0.f, y1 = 0.f, y2 = 0.f;
#pragma unroll
  for (int v = 0; v < 32; v++) {
    float r = R[v][lane], s = S[v][lane];
    y0 += __shfl(a0, v, 32) * r + __shfl(b0, v, 32) * s;
    y1 += __shfl(a1, v, 32) * r + __shfl(b1, v, 32) * s;
    y2 += __shfl(a2, v, 32) * r + __shfl(b2, v, 32) * s;
  }
  float nrm = sqrtf(y0 * y0 + y1 * y1 + y2 * y2);
  float t = tanhf(nrm);
  float* op = out + (size_t)grp * 96;
  op[lane]      = y0 * t;
  op[32 + lane] = y1 * t;
  op[64 + lane] = y2 * t;
}

// ---------------------------------------------------------------- launch
extern "C" void kernel_launch(void* const* d_in, const int* in_sizes, int n_in,
                              void* d_out, int out_size, void* d_ws, size_t ws_size,
                              hipStream_t stream) {
  const float* xn      = (const float*)d_in[0];
  const float* xn_attr = (const float*)d_in[1];
  const float* xe_attr = (const float*)d_in[2];
  const int*   xe_src  = (const int*)d_in[3];
  const int*   xe_dst  = (const int*)d_in[4];
  const float* ms_M    = (const float*)d_in[5];
  const float* ms_w    = (const float*)d_in[6];
  const float* fc1_w   = (const float*)d_in[7];
  const float* fc1_b   = (const float*)d_in[8];
  const float* fc2_w   = (const float*)d_in[9];
  const float* fc2_b   = (const float*)d_in[10];
  const float* n2e_M1  = (const float*)d_in[11];
  const float* n2e_M2  = (const float*)d_in[12];
  const float* vv_M1   = (const float*)d_in[13];
  const float* vv_M2   = (const float*)d_in[14];
  const float* e2n_M1  = (const float*)d_in[15];
  const float* e2n_M2  = (const float*)d_in[16];

  int n_nodes = in_sizes[0] / 96;
  int n_edges = in_sizes[2];

  char* base = (char*)d_ws;
  float* PQRS = (float*)base;                                   // 16 KB
  unsigned short* xn2b = (unsigned short*)(base + 16384);       // 9.6 MB bf16 nodes
  float* acc1 = (float*)(base + 16384 + (size_t)n_nodes * 96 * 2);
  float* acc2 = acc1 + (size_t)n_nodes * 96;

  prep_mats_kernel<<<1, 1024, 0, stream>>>(n2e_M1, n2e_M2, vv_M1, vv_M2,
                                           e2n_M1, e2n_M2, PQRS);

  int nblk = (n_nodes + 7) / 8;
  node_premix_kernel<<<nblk, 256, 0, stream>>>(xn, xn_attr, ms_M, ms_w, xn2b, n_nodes);

  hipMemsetAsync(acc1, 0, (size_t)n_nodes * 96 * 2 * sizeof(float), stream);

  edge_mfma_kernel<<<4096, 256, 0, stream>>>(xn2b, xe_attr, xe_src, xe_dst,
                                             fc1_w, fc1_b, fc2_w, fc2_b,
                                             PQRS, PQRS + 1024, acc1, acc2, n_edges);

  node_post_kernel<<<nblk, 256, 0, stream>>>(acc1, acc2, PQRS + 2048, PQRS + 3072,
                                             (float*)d_out, n_nodes);
}